// Round 2
// baseline (1201.859 us; speedup 1.0000x reference)
//
#include <hip/hip_runtime.h>
#include <hip/hip_bf16.h>

// Spatial RNN, 4 directions, R=8, C=64.
// One block per (direction, line). Reversed directions via negative strides so
// the recurrence is always t[p] = relu(t[p-1] @ W), t[-1] = 0.
//
// v3 (sync + occupancy + swizzle):
//  - Contiguous wave ownership: wave wv owns pixels [48wv, 48wv+48). In-place
//    t updates are wave-private except ONE boundary pixel per wave per step,
//    passed through a parity-double-buffered bnd area (8 rows x 128B).
//    -> ONE __syncthreads per step (was 2).
//  - 128B rows with 16B-granule XOR swizzle (g' = g ^ (slot&7)):
//    b128 reads = 8 lanes/bank (minimum, conflict-free),
//    b64 writes = 4 lanes/bank (minimum, conflict-free).
//    LDS = 25,600B -> 6 blocks/CU with __launch_bounds__(256,6) = 24 waves/CU.
//    Boundary lanes (l16==0 read / l16==15 write) naturally get swz=0, so bnd
//    rows are linear with the SAME address formula (only base differs).
//  - 1-D grid, batch = bid&7: each XCD works one batch (L2 locality), and the
//    4 directions of a line are temporally adjacent on the same XCD.

#define HD 192
#define CH 64
#define RSTEPS 8
#define TS 64               // shorts per row = 128B, XOR-swizzled
#define SLOTS 192           // slot p+1 holds t[p]; slot 0 = t[-1] = 0
#define BND (SLOTS * TS)    // 8 boundary rows: row = parity*4 + wave

typedef __attribute__((ext_vector_type(8))) short short8v;
typedef __attribute__((ext_vector_type(4))) float float4v;

static __device__ __forceinline__ short f2bf_rne(float f) {
    unsigned u = __float_as_uint(f);
    u += 0x7FFFu + ((u >> 16) & 1u);
    return (short)(u >> 16);
}

__global__ __launch_bounds__(256, 6) void spatial_rnn_kernel(
    const float* __restrict__ x,
    const float* __restrict__ Wl,
    const float* __restrict__ Wr,
    const float* __restrict__ Wu,
    const float* __restrict__ Wd,
    float* __restrict__ out)
{
    __shared__ __align__(16) short tb[SLOTS * TS + 8 * TS];   // 25,600 B

    const int tid = threadIdx.x;
    const int bid = blockIdx.x;
    // XCD co-location: batch = bid&7 (one batch per XCD), then per XCD the
    // 4 directions of a line are consecutive in dispatch order.
    const int b   = bid & 7;
    const int idx = bid >> 3;
    const int dir = idx & 3;
    const int rc  = idx >> 2;          // row (L/R) or column (U/D), [0,192)

    const float* Wp = (dir == 0) ? Wl : (dir == 1) ? Wr : (dir == 2) ? Wu : Wd;

    int xbase, xstride, obase, ostride;
    if (dir == 0) {        // left: out[w] uses in[w-1]; forward along w
        xbase   = (b * HD + rc) * HD * CH;
        xstride = CH;
        obase   = (b * HD + rc) * HD * 256;
        ostride = 256;
    } else if (dir == 1) { // right: out[w] uses in[w+1]; reversed along w
        xbase   = ((b * HD + rc) * HD + (HD - 1)) * CH;
        xstride = -CH;
        obase   = ((b * HD + rc) * HD + (HD - 1)) * 256 + 64;
        ostride = -256;
    } else if (dir == 2) { // up: out[h] uses in[h-1]; forward along h
        xbase   = b * HD * HD * CH + rc * CH;
        xstride = HD * CH;
        obase   = b * HD * HD * 256 + rc * 256 + 128;
        ostride = HD * 256;
    } else {               // down: out[h] uses in[h+1]; reversed along h
        xbase   = ((b * HD + (HD - 1)) * HD + rc) * CH;
        xstride = -HD * CH;
        obase   = ((b * HD + (HD - 1)) * HD + rc) * 256 + 192;
        ostride = -HD * 256;
    }

    const int lane = tid & 63;
    const int wv   = tid >> 6;
    const int q4   = lane >> 4;
    const int l16  = lane & 15;

    // zero slot-0 row (t[-1]); swizzled zeros are still zeros
    if (tid < 32) ((int*)tb)[tid] = 0;

    // ---- x fragment loads: acc init (folds final "+x") + t0 -> LDS ----
    float4v acc[3][4];
    #pragma unroll
    for (int i = 0; i < 3; ++i) {
        const int p   = (3 * wv + i) * 16 + l16;     // contiguous ownership
        const int wsz = (l16 + 1) & 7;               // == (slot&7); 0 at boundary
        int wbase = (p + 1) * TS;
        if (i == 2 && l16 == 15) wbase = BND + (4 + wv) * TS;  // parity-1 bnd
        #pragma unroll
        for (int dt = 0; dt < 4; ++dt) {
            const float4 v = *(const float4*)(x + xbase + p * xstride + dt * 16 + q4 * 4);
            acc[i][dt] = (float4v){v.x, v.y, v.z, v.w};
            __hip_bfloat162 h01 = __float22bfloat162_rn(make_float2(v.x, v.y));
            __hip_bfloat162 h23 = __float22bfloat162_rn(make_float2(v.z, v.w));
            uint2 wpk;
            __builtin_memcpy(&wpk.x, &h01, 4);
            __builtin_memcpy(&wpk.y, &h23, 4);
            *(uint2*)(tb + wbase + (((2 * dt + (q4 >> 1)) ^ wsz) << 3) + ((q4 & 1) << 2)) = wpk;
        }
    }

    // ---- W fragments (A operand): A[d][c] = W[c][d] ----
    short8v Af[2][4];
    #pragma unroll
    for (int kc = 0; kc < 2; ++kc)
        #pragma unroll
        for (int dt = 0; dt < 4; ++dt)
            #pragma unroll
            for (int j = 0; j < 8; ++j)
                Af[kc][dt][j] = f2bf_rne(Wp[(kc * 32 + q4 * 8 + j) * CH + dt * 16 + l16]);

    __syncthreads();

    // ---- 8 recurrent steps, in place, ONE barrier per step ----
    for (int k = 0; k < RSTEPS; ++k) {
        short8v B0[3], B1[3];
        const int prb = ((k & 1) ^ 1) << 2;          // read-parity bnd offset
        #pragma unroll
        for (int i = 0; i < 3; ++i) {
            const int slot = (3 * wv + i) * 16 + l16;   // holds t_prev[slot-1]
            const int sz   = l16 & 7;                    // == slot&7; 0 at boundary
            int base = slot * TS;
            if (i == 0 && l16 == 0 && wv > 0) base = BND + (prb + wv - 1) * TS;
            B0[i] = *(const short8v*)(tb + base + ((q4 ^ sz) << 3));
            B1[i] = *(const short8v*)(tb + base + (((q4 + 4) ^ sz) << 3));
        }
        // wave-private in-place writes (LDS pipe is in-order per wave)
        #pragma unroll
        for (int i = 0; i < 3; ++i) {
            const int wsz = (l16 + 1) & 7;
            int wbase = ((3 * wv + i) * 16 + l16 + 1) * TS;
            if (i == 2 && l16 == 15) wbase = BND + (((k & 1) << 2) + wv) * TS;
            #pragma unroll
            for (int dt = 0; dt < 4; ++dt) {
                float4v d = {0.f, 0.f, 0.f, 0.f};
                d = __builtin_amdgcn_mfma_f32_16x16x32_bf16(Af[0][dt], B0[i], d, 0, 0, 0);
                d = __builtin_amdgcn_mfma_f32_16x16x32_bf16(Af[1][dt], B1[i], d, 0, 0, 0);
                float v0 = fmaxf(d[0], 0.f);
                float v1 = fmaxf(d[1], 0.f);
                float v2 = fmaxf(d[2], 0.f);
                float v3 = fmaxf(d[3], 0.f);
                acc[i][dt][0] += v0; acc[i][dt][1] += v1;
                acc[i][dt][2] += v2; acc[i][dt][3] += v3;
                if (k < RSTEPS - 1) {
                    __hip_bfloat162 h01 = __float22bfloat162_rn(make_float2(v0, v1));
                    __hip_bfloat162 h23 = __float22bfloat162_rn(make_float2(v2, v3));
                    uint2 wpk;
                    __builtin_memcpy(&wpk.x, &h01, 4);
                    __builtin_memcpy(&wpk.y, &h23, 4);
                    *(uint2*)(tb + wbase + (((2 * dt + (q4 >> 1)) ^ wsz) << 3) + ((q4 & 1) << 2)) = wpk;
                }
            }
        }
        if (k < RSTEPS - 1) __syncthreads();
    }

    // ---- store: out = acc (x folded in at init) ----
    // lanes q4=0..3 of one pixel cover 64B contiguous -> full write sectors
    #pragma unroll
    for (int i = 0; i < 3; ++i) {
        const int p = (3 * wv + i) * 16 + l16;
        #pragma unroll
        for (int dt = 0; dt < 4; ++dt) {
            float4 o;
            o.x = acc[i][dt][0]; o.y = acc[i][dt][1];
            o.z = acc[i][dt][2]; o.w = acc[i][dt][3];
            *(float4*)(out + obase + p * ostride + dt * 16 + q4 * 4) = o;
        }
    }
}

extern "C" void kernel_launch(void* const* d_in, const int* in_sizes, int n_in,
                              void* d_out, int out_size, void* d_ws, size_t ws_size,
                              hipStream_t stream) {
    const float* x  = (const float*)d_in[0];
    const float* Wl = (const float*)d_in[1];
    const float* Wr = (const float*)d_in[2];
    const float* Wu = (const float*)d_in[3];
    const float* Wd = (const float*)d_in[4];
    float* outp = (float*)d_out;
    dim3 grid(8 * HD * 4);
    spatial_rnn_kernel<<<grid, 256, 0, stream>>>(x, Wl, Wr, Wu, Wd, outp);
}

// Round 3
// 980.824 us; speedup vs baseline: 1.2254x; 1.2254x over previous
//
#include <hip/hip_runtime.h>
#include <hip/hip_bf16.h>

// Spatial RNN, 4 directions, R=8, C=64.
// One block per (direction, line). Reversed directions via negative strides so
// the recurrence is always t[p] = relu(t[p-1] @ W), t[-1] = 0.
//
// v4 = v3 with the launch-bounds spill fixed:
//  - v3's __launch_bounds__(256,6) capped VGPRs at ~80 -> compiler spilled
//    acc/Af to scratch (VGPR_Count 40, hbm_bytes 0.59GB -> 4.2GB, 943us).
//    (256,5) caps at ~96-102; the live set measured 88 in v2 -> fits, no
//    spill, and keeps 5 blocks/CU (20 waves, +25% vs v2's 4 blocks).
//  - Contiguous wave ownership: wave wv owns pixels [48wv, 48wv+48). In-place
//    t updates are wave-private except ONE boundary pixel per wave per step,
//    passed through a parity-double-buffered bnd area (8 rows x 128B).
//    -> ONE __syncthreads per step.
//  - 128B rows with 16B-granule XOR swizzle (g' = g ^ (slot&7)):
//    b128 reads = 8 lanes/bank (minimum), b64 writes = 4 lanes/bank (minimum).
//    LDS = 25,600B -> 5 blocks/CU fit easily (128KB of 160KB).
//  - 1-D grid, batch = bid&7: one batch per XCD (L2 locality).

#define HD 192
#define CH 64
#define RSTEPS 8
#define TS 64               // shorts per row = 128B, XOR-swizzled
#define SLOTS 192           // slot p+1 holds t[p]; slot 0 = t[-1] = 0
#define BND (SLOTS * TS)    // 8 boundary rows: row = parity*4 + wave

typedef __attribute__((ext_vector_type(8))) short short8v;
typedef __attribute__((ext_vector_type(4))) float float4v;

static __device__ __forceinline__ short f2bf_rne(float f) {
    unsigned u = __float_as_uint(f);
    u += 0x7FFFu + ((u >> 16) & 1u);
    return (short)(u >> 16);
}

__global__ __launch_bounds__(256, 5) void spatial_rnn_kernel(
    const float* __restrict__ x,
    const float* __restrict__ Wl,
    const float* __restrict__ Wr,
    const float* __restrict__ Wu,
    const float* __restrict__ Wd,
    float* __restrict__ out)
{
    __shared__ __align__(16) short tb[SLOTS * TS + 8 * TS];   // 25,600 B

    const int tid = threadIdx.x;
    const int bid = blockIdx.x;
    // XCD co-location: batch = bid&7 (one batch per XCD), then per XCD the
    // 4 directions of a line are consecutive in dispatch order.
    const int b   = bid & 7;
    const int idx = bid >> 3;
    const int dir = idx & 3;
    const int rc  = idx >> 2;          // row (L/R) or column (U/D), [0,192)

    const float* Wp = (dir == 0) ? Wl : (dir == 1) ? Wr : (dir == 2) ? Wu : Wd;

    int xbase, xstride, obase, ostride;
    if (dir == 0) {        // left: out[w] uses in[w-1]; forward along w
        xbase   = (b * HD + rc) * HD * CH;
        xstride = CH;
        obase   = (b * HD + rc) * HD * 256;
        ostride = 256;
    } else if (dir == 1) { // right: out[w] uses in[w+1]; reversed along w
        xbase   = ((b * HD + rc) * HD + (HD - 1)) * CH;
        xstride = -CH;
        obase   = ((b * HD + rc) * HD + (HD - 1)) * 256 + 64;
        ostride = -256;
    } else if (dir == 2) { // up: out[h] uses in[h-1]; forward along h
        xbase   = b * HD * HD * CH + rc * CH;
        xstride = HD * CH;
        obase   = b * HD * HD * 256 + rc * 256 + 128;
        ostride = HD * 256;
    } else {               // down: out[h] uses in[h+1]; reversed along h
        xbase   = ((b * HD + (HD - 1)) * HD + rc) * CH;
        xstride = -HD * CH;
        obase   = ((b * HD + (HD - 1)) * HD + rc) * 256 + 192;
        ostride = -HD * 256;
    }

    const int lane = tid & 63;
    const int wv   = tid >> 6;
    const int q4   = lane >> 4;
    const int l16  = lane & 15;

    // zero slot-0 row (t[-1]); swizzled zeros are still zeros
    if (tid < 32) ((int*)tb)[tid] = 0;

    // ---- x fragment loads: acc init (folds final "+x") + t0 -> LDS ----
    float4v acc[3][4];
    #pragma unroll
    for (int i = 0; i < 3; ++i) {
        const int p   = (3 * wv + i) * 16 + l16;     // contiguous ownership
        const int wsz = (l16 + 1) & 7;               // == (slot&7); 0 at boundary
        int wbase = (p + 1) * TS;
        if (i == 2 && l16 == 15) wbase = BND + (4 + wv) * TS;  // parity-1 bnd
        #pragma unroll
        for (int dt = 0; dt < 4; ++dt) {
            const float4 v = *(const float4*)(x + xbase + p * xstride + dt * 16 + q4 * 4);
            acc[i][dt] = (float4v){v.x, v.y, v.z, v.w};
            __hip_bfloat162 h01 = __float22bfloat162_rn(make_float2(v.x, v.y));
            __hip_bfloat162 h23 = __float22bfloat162_rn(make_float2(v.z, v.w));
            uint2 wpk;
            __builtin_memcpy(&wpk.x, &h01, 4);
            __builtin_memcpy(&wpk.y, &h23, 4);
            *(uint2*)(tb + wbase + (((2 * dt + (q4 >> 1)) ^ wsz) << 3) + ((q4 & 1) << 2)) = wpk;
        }
    }

    // ---- W fragments (A operand): A[d][c] = W[c][d] ----
    short8v Af[2][4];
    #pragma unroll
    for (int kc = 0; kc < 2; ++kc)
        #pragma unroll
        for (int dt = 0; dt < 4; ++dt)
            #pragma unroll
            for (int j = 0; j < 8; ++j)
                Af[kc][dt][j] = f2bf_rne(Wp[(kc * 32 + q4 * 8 + j) * CH + dt * 16 + l16]);

    __syncthreads();

    // ---- 8 recurrent steps, in place, ONE barrier per step ----
    for (int k = 0; k < RSTEPS; ++k) {
        short8v B0[3], B1[3];
        const int prb = ((k & 1) ^ 1) << 2;          // read-parity bnd offset
        #pragma unroll
        for (int i = 0; i < 3; ++i) {
            const int slot = (3 * wv + i) * 16 + l16;   // holds t_prev[slot-1]
            const int sz   = l16 & 7;                    // == slot&7; 0 at boundary
            int base = slot * TS;
            if (i == 0 && l16 == 0 && wv > 0) base = BND + (prb + wv - 1) * TS;
            B0[i] = *(const short8v*)(tb + base + ((q4 ^ sz) << 3));
            B1[i] = *(const short8v*)(tb + base + (((q4 + 4) ^ sz) << 3));
        }
        // wave-private in-place writes (LDS pipe is in-order per wave)
        #pragma unroll
        for (int i = 0; i < 3; ++i) {
            const int wsz = (l16 + 1) & 7;
            int wbase = ((3 * wv + i) * 16 + l16 + 1) * TS;
            if (i == 2 && l16 == 15) wbase = BND + (((k & 1) << 2) + wv) * TS;
            #pragma unroll
            for (int dt = 0; dt < 4; ++dt) {
                float4v d = {0.f, 0.f, 0.f, 0.f};
                d = __builtin_amdgcn_mfma_f32_16x16x32_bf16(Af[0][dt], B0[i], d, 0, 0, 0);
                d = __builtin_amdgcn_mfma_f32_16x16x32_bf16(Af[1][dt], B1[i], d, 0, 0, 0);
                float v0 = fmaxf(d[0], 0.f);
                float v1 = fmaxf(d[1], 0.f);
                float v2 = fmaxf(d[2], 0.f);
                float v3 = fmaxf(d[3], 0.f);
                acc[i][dt][0] += v0; acc[i][dt][1] += v1;
                acc[i][dt][2] += v2; acc[i][dt][3] += v3;
                if (k < RSTEPS - 1) {
                    __hip_bfloat162 h01 = __float22bfloat162_rn(make_float2(v0, v1));
                    __hip_bfloat162 h23 = __float22bfloat162_rn(make_float2(v2, v3));
                    uint2 wpk;
                    __builtin_memcpy(&wpk.x, &h01, 4);
                    __builtin_memcpy(&wpk.y, &h23, 4);
                    *(uint2*)(tb + wbase + (((2 * dt + (q4 >> 1)) ^ wsz) << 3) + ((q4 & 1) << 2)) = wpk;
                }
            }
        }
        if (k < RSTEPS - 1) __syncthreads();
    }

    // ---- store: out = acc (x folded in at init) ----
    // lanes q4=0..3 of one pixel cover 64B contiguous -> full write sectors
    #pragma unroll
    for (int i = 0; i < 3; ++i) {
        const int p = (3 * wv + i) * 16 + l16;
        #pragma unroll
        for (int dt = 0; dt < 4; ++dt) {
            float4 o;
            o.x = acc[i][dt][0]; o.y = acc[i][dt][1];
            o.z = acc[i][dt][2]; o.w = acc[i][dt][3];
            *(float4*)(out + obase + p * ostride + dt * 16 + q4 * 4) = o;
        }
    }
}

extern "C" void kernel_launch(void* const* d_in, const int* in_sizes, int n_in,
                              void* d_out, int out_size, void* d_ws, size_t ws_size,
                              hipStream_t stream) {
    const float* x  = (const float*)d_in[0];
    const float* Wl = (const float*)d_in[1];
    const float* Wr = (const float*)d_in[2];
    const float* Wu = (const float*)d_in[3];
    const float* Wd = (const float*)d_in[4];
    float* outp = (float*)d_out;
    dim3 grid(8 * HD * 4);
    spatial_rnn_kernel<<<grid, 256, 0, stream>>>(x, Wl, Wr, Wu, Wd, outp);
}

// Round 4
// 431.636 us; speedup vs baseline: 2.7844x; 2.2723x over previous
//
#include <hip/hip_runtime.h>
#include <hip/hip_bf16.h>

// Spatial RNN, 4 directions, R=8, C=64.
// One block per (direction, line). Reversed directions via negative strides so
// the recurrence is always t[p] = relu(t[p-1] @ W), t[-1] = 0.
//
// v5 = v3 structure with the spill actually fixed:
//  - __launch_bounds__(256,4): VGPR cap 128. (256,5)/(256,6) capped the
//    unified VGPR/AGPR file at ~102/~85 -> arch/accum split left ~48 arch
//    regs -> acc/Af spilled to scratch (hbm_bytes 3.2-4.2GB, 720-943us).
//    v2 proved 88 VGPRs / no spill at this bound.
//  - Descending tile order (i=2..0), per-tile read->MFMA->write: tile i's
//    writes (slots 48wv+16i+1 .. +16) are disjoint from tile i-1's reads
//    (slots 48wv+16(i-1) .. +15); same-tile read precedes write in the
//    in-order per-wave LDS pipe. B-fragment live regs 24 -> 8.
//  - Contiguous wave ownership + parity-double-buffered boundary rows
//    -> ONE __syncthreads per step.
//  - 128B rows, 16B-granule XOR swizzle (g' = g ^ (slot&7)): b128 reads and
//    b64 writes both at the wave64 minimum lanes/bank. LDS = 25,600B.
//  - 1-D grid, batch = bid&7: one batch per XCD (L2 locality); L/R (and U/D)
//    of the same line are dispatch-adjacent on the same XCD.

#define HD 192
#define CH 64
#define RSTEPS 8
#define TS 64               // shorts per row = 128B, XOR-swizzled
#define SLOTS 192           // slot p+1 holds t[p]; slot 0 = t[-1] = 0
#define BND (SLOTS * TS)    // 8 boundary rows: row = parity*4 + wave

typedef __attribute__((ext_vector_type(8))) short short8v;
typedef __attribute__((ext_vector_type(4))) float float4v;

static __device__ __forceinline__ short f2bf_rne(float f) {
    unsigned u = __float_as_uint(f);
    u += 0x7FFFu + ((u >> 16) & 1u);
    return (short)(u >> 16);
}

__global__ __launch_bounds__(256, 4) void spatial_rnn_kernel(
    const float* __restrict__ x,
    const float* __restrict__ Wl,
    const float* __restrict__ Wr,
    const float* __restrict__ Wu,
    const float* __restrict__ Wd,
    float* __restrict__ out)
{
    __shared__ __align__(16) short tb[SLOTS * TS + 8 * TS];   // 25,600 B

    const int tid = threadIdx.x;
    const int bid = blockIdx.x;
    const int b   = bid & 7;
    const int idx = bid >> 3;
    const int dir = idx & 3;
    const int rc  = idx >> 2;          // row (L/R) or column (U/D), [0,192)

    const float* Wp = (dir == 0) ? Wl : (dir == 1) ? Wr : (dir == 2) ? Wu : Wd;

    int xbase, xstride, obase, ostride;
    if (dir == 0) {        // left: out[w] uses in[w-1]; forward along w
        xbase   = (b * HD + rc) * HD * CH;
        xstride = CH;
        obase   = (b * HD + rc) * HD * 256;
        ostride = 256;
    } else if (dir == 1) { // right: out[w] uses in[w+1]; reversed along w
        xbase   = ((b * HD + rc) * HD + (HD - 1)) * CH;
        xstride = -CH;
        obase   = ((b * HD + rc) * HD + (HD - 1)) * 256 + 64;
        ostride = -256;
    } else if (dir == 2) { // up: out[h] uses in[h-1]; forward along h
        xbase   = b * HD * HD * CH + rc * CH;
        xstride = HD * CH;
        obase   = b * HD * HD * 256 + rc * 256 + 128;
        ostride = HD * 256;
    } else {               // down: out[h] uses in[h+1]; reversed along h
        xbase   = ((b * HD + (HD - 1)) * HD + rc) * CH;
        xstride = -HD * CH;
        obase   = ((b * HD + (HD - 1)) * HD + rc) * 256 + 192;
        ostride = -HD * 256;
    }

    const int lane = tid & 63;
    const int wv   = tid >> 6;
    const int q4   = lane >> 4;
    const int l16  = lane & 15;

    // zero slot-0 row (t[-1]); swizzled zeros are still zeros
    if (tid < 32) ((int*)tb)[tid] = 0;

    // ---- x fragment loads: acc init (folds final "+x") + t0 -> LDS ----
    float4v acc[3][4];
    #pragma unroll
    for (int i = 0; i < 3; ++i) {
        const int p   = (3 * wv + i) * 16 + l16;     // contiguous ownership
        const int wsz = (l16 + 1) & 7;               // == (slot&7); 0 at boundary
        int wbase = (p + 1) * TS;
        if (i == 2 && l16 == 15) wbase = BND + (4 + wv) * TS;  // parity-1 bnd
        #pragma unroll
        for (int dt = 0; dt < 4; ++dt) {
            const float4 v = *(const float4*)(x + xbase + p * xstride + dt * 16 + q4 * 4);
            acc[i][dt] = (float4v){v.x, v.y, v.z, v.w};
            __hip_bfloat162 h01 = __float22bfloat162_rn(make_float2(v.x, v.y));
            __hip_bfloat162 h23 = __float22bfloat162_rn(make_float2(v.z, v.w));
            uint2 wpk;
            __builtin_memcpy(&wpk.x, &h01, 4);
            __builtin_memcpy(&wpk.y, &h23, 4);
            *(uint2*)(tb + wbase + (((2 * dt + (q4 >> 1)) ^ wsz) << 3) + ((q4 & 1) << 2)) = wpk;
        }
    }

    // ---- W fragments (A operand): A[d][c] = W[c][d] ----
    short8v Af[2][4];
    #pragma unroll
    for (int kc = 0; kc < 2; ++kc)
        #pragma unroll
        for (int dt = 0; dt < 4; ++dt)
            #pragma unroll
            for (int j = 0; j < 8; ++j)
                Af[kc][dt][j] = f2bf_rne(Wp[(kc * 32 + q4 * 8 + j) * CH + dt * 16 + l16]);

    __syncthreads();

    // ---- 8 recurrent steps, in place, ONE barrier per step ----
    // Tiles processed DESCENDING so each tile's write never touches a
    // later-read slot; B fragments live only within one tile (8 VGPRs).
    for (int k = 0; k < RSTEPS; ++k) {
        const int prb = ((k & 1) ^ 1) << 2;          // read-parity bnd offset
        #pragma unroll
        for (int i = 2; i >= 0; --i) {
            const int slot = (3 * wv + i) * 16 + l16;   // holds t_prev[slot-1]
            const int sz   = l16 & 7;                    // == slot&7; 0 at boundary
            int base = slot * TS;
            if (i == 0 && l16 == 0 && wv > 0) base = BND + (prb + wv - 1) * TS;
            short8v B0 = *(const short8v*)(tb + base + ((q4 ^ sz) << 3));
            short8v B1 = *(const short8v*)(tb + base + (((q4 + 4) ^ sz) << 3));

            const int wsz = (l16 + 1) & 7;
            int wbase = (slot + 1) * TS;
            if (i == 2 && l16 == 15) wbase = BND + (((k & 1) << 2) + wv) * TS;
            #pragma unroll
            for (int dt = 0; dt < 4; ++dt) {
                float4v d = {0.f, 0.f, 0.f, 0.f};
                d = __builtin_amdgcn_mfma_f32_16x16x32_bf16(Af[0][dt], B0, d, 0, 0, 0);
                d = __builtin_amdgcn_mfma_f32_16x16x32_bf16(Af[1][dt], B1, d, 0, 0, 0);
                float v0 = fmaxf(d[0], 0.f);
                float v1 = fmaxf(d[1], 0.f);
                float v2 = fmaxf(d[2], 0.f);
                float v3 = fmaxf(d[3], 0.f);
                acc[i][dt][0] += v0; acc[i][dt][1] += v1;
                acc[i][dt][2] += v2; acc[i][dt][3] += v3;
                if (k < RSTEPS - 1) {
                    __hip_bfloat162 h01 = __float22bfloat162_rn(make_float2(v0, v1));
                    __hip_bfloat162 h23 = __float22bfloat162_rn(make_float2(v2, v3));
                    uint2 wpk;
                    __builtin_memcpy(&wpk.x, &h01, 4);
                    __builtin_memcpy(&wpk.y, &h23, 4);
                    *(uint2*)(tb + wbase + (((2 * dt + (q4 >> 1)) ^ wsz) << 3) + ((q4 & 1) << 2)) = wpk;
                }
            }
        }
        if (k < RSTEPS - 1) __syncthreads();
    }

    // ---- store: out = acc (x folded in at init) ----
    // lanes q4=0..3 of one pixel cover 64B contiguous -> full write sectors
    #pragma unroll
    for (int i = 0; i < 3; ++i) {
        const int p = (3 * wv + i) * 16 + l16;
        #pragma unroll
        for (int dt = 0; dt < 4; ++dt) {
            float4 o;
            o.x = acc[i][dt][0]; o.y = acc[i][dt][1];
            o.z = acc[i][dt][2]; o.w = acc[i][dt][3];
            *(float4*)(out + obase + p * ostride + dt * 16 + q4 * 4) = o;
        }
    }
}

extern "C" void kernel_launch(void* const* d_in, const int* in_sizes, int n_in,
                              void* d_out, int out_size, void* d_ws, size_t ws_size,
                              hipStream_t stream) {
    const float* x  = (const float*)d_in[0];
    const float* Wl = (const float*)d_in[1];
    const float* Wr = (const float*)d_in[2];
    const float* Wu = (const float*)d_in[3];
    const float* Wd = (const float*)d_in[4];
    float* outp = (float*)d_out;
    dim3 grid(8 * HD * 4);
    spatial_rnn_kernel<<<grid, 256, 0, stream>>>(x, Wl, Wr, Wu, Wd, outp);
}